// Round 4
// baseline (247.483 us; speedup 1.0000x reference)
//
#include <hip/hip_runtime.h>

typedef unsigned short ushort_t;
typedef unsigned int uint_t;

typedef __bf16 bf16x8 __attribute__((ext_vector_type(8)));
typedef float f32x4 __attribute__((ext_vector_type(4)));

#define N_NODES 50000
#define N_EDGES 800000
#define DIM 128
#define NUM_GRAPHS 512
#define LDA 136  // padded LDS row stride in bf16 elems (128+8)

// ELL adjacency: fixed 64 slots per node (in-degree ~Poisson(16), max ~35;
// P(deg>64) astronomically small. Guarded anyway: overflow slots dropped.)
#define ELL_CAP 64

// Two-phase edge build:
//  Pass A (in prep_all): partition edges into 8 dst-range FIFOs (compact int2
//    pairs) via LDS counters + 1 global atomic per block per group.
//  Pass B (scatter_kernel): group g = blockIdx&7 (one XCD per group under
//    round-robin dispatch) scatters ITS fifo into cnt/ell with 100% lane
//    efficiency and XCD-local atomics.
// Round-3 lesson: bucketed single-kernel scatter paid 8x divergent scatter
// instructions at ~12% lane efficiency -> 44us at 25% HBM.
#define EDGE_GROUPS 8
#define EDGE_BUCKET ((N_NODES + EDGE_GROUPS - 1) / EDGE_GROUPS)  // 6250
#define A_CHUNK 2048
#define A_BLOCKS ((N_EDGES + A_CHUNK - 1) / A_CHUNK)             // 391
#define FIFO_CAP 110592   // avg 100K/group, sigma ~300; never overflows (guarded)

// prep_all block ranges (edge-partition blocks first: critical path)
#define PREP_X_BLOCKS 6250                    // conv_x: only does work when f32 input
#define PREP_W_BLOCKS 256                     // wperm: 65536 / 256
#define PREP_B_BLOCKS 196                     // batch: 50000 / 256
#define PREP_TOTAL (A_BLOCKS + PREP_X_BLOCKS + PREP_W_BLOCKS + PREP_B_BLOCKS + 1)

#define SCATTER_BLOCKS 512   // 64 sub-blocks x 8 groups

__device__ __forceinline__ float bf2f(ushort_t u) {
    return __uint_as_float(((uint_t)u) << 16);
}
__device__ __forceinline__ ushort_t f2bf(float f) {
    uint_t u = __float_as_uint(f);
    u = (u + 0x7FFF + ((u >> 16) & 1)) >> 16;  // RNE
    return (ushort_t)u;
}
__device__ __forceinline__ bf16x8 as_bf16x8(uint4 v) {
    return __builtin_bit_cast(bf16x8, v);
}

// ---------------- zero (degree + gsum + fifo counters) + dtype detection ---------
__global__ void zero_detect_kernel(int* cnt, float* gsum, int* gcnt, const void* xraw,
                                   const void* eiraw, int* flags) {
    int i = blockIdx.x * 256 + threadIdx.x;
    if (i < N_NODES) cnt[i] = 0;
    if (i < NUM_GRAPHS * DIM) gsum[i] = 0.f;
    if (i < EDGE_GROUPS) gcnt[i] = 0;
    if (i == 0) {
        const ushort_t* u = (const ushort_t*)xraw;
        int extreme = 0;
        for (int k = 0; k < 128; ++k) {
            int e = (u[k] >> 7) & 0xFF;
            if (e >= 0xC0) extreme++;  // |x| >= 2^65: impossible for bf16 N(0,1)
        }
        flags[0] = (extreme > 8) ? 1 : 0;
        const int* p = (const int*)eiraw;
        int nonzero = 0;
        for (int k = 1; k < 64; k += 2) nonzero += (p[k] != 0);
        flags[1] = (nonzero == 0) ? 1 : 0;  // all high-halves zero => int64
    }
}

// ---------------- merged canonicalization + edge partition (pass A) ----------------
__global__ __launch_bounds__(256) void prep_all_kernel(
    const void* xraw, const void* braw, const void* eiraw,
    const void* W0, const void* W1, const void* W2, const void* W3,
    const void* pb1a, const void* pb1b, const void* pb2a, const void* pb2b,
    const void* pWfc, const void* pbfc, const int* __restrict__ flags,
    ushort_t* __restrict__ xout, ushort_t* __restrict__ wpout,
    int* __restrict__ batch32, float* __restrict__ params,
    int* __restrict__ gcnt, int2* __restrict__ fifo) {
    __shared__ int lcnt[EDGE_GROUPS];
    __shared__ int lbase[EDGE_GROUPS];
    int b = blockIdx.x;
    int tid = threadIdx.x;
    if (b < A_BLOCKS) {
        if (tid < EDGE_GROUPS) lcnt[tid] = 0;
        __syncthreads();
        const int* p = (const int*)eiraw;
        int i64 = flags[1];
        int base_e = b * A_CHUNK;
        int g[8], r[8], sv[8], dv[8];
#pragma unroll
        for (int k = 0; k < 8; ++k) {
            int e = base_e + k * 256 + tid;
            int valid = e < N_EDGES;
            int s = 0, d = 0;
            if (valid) {
                if (i64) { s = p[2 * e]; d = p[2 * (N_EDGES + e)]; }
                else     { s = p[e];     d = p[N_EDGES + e]; }
            }
            sv[k] = s; dv[k] = d;
            g[k] = valid ? (d / EDGE_BUCKET) : -1;
            r[k] = 0;
            if (valid) r[k] = atomicAdd(&lcnt[g[k]], 1);
        }
        __syncthreads();
        if (tid < EDGE_GROUPS) lbase[tid] = atomicAdd(&gcnt[tid], lcnt[tid]);
        __syncthreads();
#pragma unroll
        for (int k = 0; k < 8; ++k) {
            if (g[k] >= 0) {
                int pos = lbase[g[k]] + r[k];
                if (pos < FIFO_CAP)
                    fifo[(size_t)g[k] * FIFO_CAP + pos] = make_int2(sv[k], dv[k]);
            }
        }
    } else if (b < A_BLOCKS + PREP_X_BLOCKS) {
        if (flags[0]) {  // only f32 input needs conversion; bf16 is read in place
            int i = (b - A_BLOCKS) * 256 + tid;
            if (i < N_NODES * DIM / 4) {
                float4 v = ((const float4*)xraw)[i];
                ushort4 o;
                o.x = f2bf(v.x); o.y = f2bf(v.y); o.z = f2bf(v.z); o.w = f2bf(v.w);
                ((ushort4*)xout)[i] = o;
            }
        }
    } else if (b < A_BLOCKS + PREP_X_BLOCKS + PREP_W_BLOCKS) {
        int gidx = (b - A_BLOCKS - PREP_X_BLOCKS) * 256 + tid;  // 0..65535
        int which = gidx >> 14;
        const void* W = (which == 0) ? W0 : (which == 1) ? W1 : (which == 2) ? W2 : W3;
        int idx = gidx & 16383;
        int j = idx & 7;
        int L = (idx >> 3) & 63;
        int t = (idx >> 9) & 7;
        int s = idx >> 12;
        int k = s * 32 + (L >> 4) * 8 + j;
        int n = t * 16 + (L & 15);
        int off = k * DIM + n;
        wpout[gidx] = flags[0] ? f2bf(((const float*)W)[off]) : ((const ushort_t*)W)[off];
    } else if (b < A_BLOCKS + PREP_X_BLOCKS + PREP_W_BLOCKS + PREP_B_BLOCKS) {
        int i = (b - A_BLOCKS - PREP_X_BLOCKS - PREP_W_BLOCKS) * 256 + tid;
        if (i < N_NODES) {
            const int* p = (const int*)braw;
            batch32[i] = flags[1] ? p[2 * i] : p[i];
        }
    } else {
        for (int i = tid; i < 770; i += 256) {
            const void* srcp;
            int j;
            if (i < 128)      { srcp = pb1a; j = i; }
            else if (i < 256) { srcp = pb1b; j = i - 128; }
            else if (i < 384) { srcp = pb2a; j = i - 256; }
            else if (i < 512) { srcp = pb2b; j = i - 384; }
            else if (i < 768) { srcp = pWfc; j = i - 512; }
            else              { srcp = pbfc; j = i - 768; }
            params[i] = flags[0] ? ((const float*)srcp)[j] : bf2f(((const ushort_t*)srcp)[j]);
        }
    }
}

// ---------------- pass B: dense per-group ELL scatter ----------------
// group = blockIdx&7 -> one XCD per group's cnt/ell region; all lanes active.
__global__ __launch_bounds__(256) void scatter_kernel(const int2* __restrict__ fifo,
                                                      const int* __restrict__ gcnt,
                                                      int* __restrict__ cnt,
                                                      int* __restrict__ ell) {
    int g = blockIdx.x & (EDGE_GROUPS - 1);
    int sub = blockIdx.x >> 3;               // 0..63
    int n = gcnt[g];
    if (n > FIFO_CAP) n = FIFO_CAP;
    const int2* f = fifo + (size_t)g * FIFO_CAP;
    for (int i = sub * 256 + threadIdx.x; i < n; i += (SCATTER_BLOCKS / EDGE_GROUPS) * 256) {
        int2 sd = f[i];
        int slot = atomicAdd(&cnt[sd.y], 1);
        if (slot < ELL_CAP) ell[sd.y * ELL_CAP + slot] = sd.x;
    }
}

// ---------------- aggregation: h[n] = feat[n] + sum_{j in in-edges} feat[src_j] ----
// Standalone (NOT fused into the GEMM): 16 nodes/block x 3125 blocks keeps
// full occupancy to hide random-gather latency (round-2 lesson: fusing into
// the 782-block MLP grid dropped occupancy to 20%, +25us). Quarter-wave
// (16 lanes) per node, uint4 per lane, unroll-8 = 32 gathers in flight/wave.
// ELL indices fetched as int4 (2 VMEM ops per 8 edges).
__global__ __launch_bounds__(256) void agg_kernel(const ushort_t* __restrict__ featA,
                                                  const void* __restrict__ featB,
                                                  const int* __restrict__ flags,
                                                  const int* __restrict__ deg,
                                                  const int* __restrict__ ell,
                                                  ushort_t* __restrict__ hout) {
    int n = blockIdx.x * 16 + (threadIdx.x >> 4);
    int lane = threadIdx.x & 15;
    if (n >= N_NODES) return;
    // flags==nullptr -> use featA; else select converted vs raw-bf16 input
    const ushort_t* feat = featA;
    if (flags && !flags[0]) feat = (const ushort_t*)featB;
    const uint4* fp = reinterpret_cast<const uint4*>(feat);  // row = 16 x uint4
    uint4 v = fp[(size_t)n * 16 + lane];
    float a0 = bf2f((ushort_t)(v.x & 0xffff));
    float a1 = bf2f((ushort_t)(v.x >> 16));
    float a2 = bf2f((ushort_t)(v.y & 0xffff));
    float a3 = bf2f((ushort_t)(v.y >> 16));
    float a4 = bf2f((ushort_t)(v.z & 0xffff));
    float a5 = bf2f((ushort_t)(v.z >> 16));
    float a6 = bf2f((ushort_t)(v.w & 0xffff));
    float a7 = bf2f((ushort_t)(v.w >> 16));
    int e1 = deg[n];
    if (e1 > ELL_CAP) e1 = ELL_CAP;
    const int4* __restrict__ rp4 = reinterpret_cast<const int4*>(ell + (size_t)n * ELL_CAP);
    const int* __restrict__ row = ell + (size_t)n * ELL_CAP;
    int j = 0;
#define ACC8(V) \
    a0 += bf2f((ushort_t)((V).x & 0xffff)); a1 += bf2f((ushort_t)((V).x >> 16)); \
    a2 += bf2f((ushort_t)((V).y & 0xffff)); a3 += bf2f((ushort_t)((V).y >> 16)); \
    a4 += bf2f((ushort_t)((V).z & 0xffff)); a5 += bf2f((ushort_t)((V).z >> 16)); \
    a6 += bf2f((ushort_t)((V).w & 0xffff)); a7 += bf2f((ushort_t)((V).w >> 16));
    for (; j + 8 <= e1; j += 8) {
        int4 ra = rp4[j >> 2];
        int4 rb = rp4[(j >> 2) + 1];
        uint4 g0 = fp[(size_t)ra.x * 16 + lane];
        uint4 g1 = fp[(size_t)ra.y * 16 + lane];
        uint4 g2 = fp[(size_t)ra.z * 16 + lane];
        uint4 g3 = fp[(size_t)ra.w * 16 + lane];
        uint4 g4 = fp[(size_t)rb.x * 16 + lane];
        uint4 g5 = fp[(size_t)rb.y * 16 + lane];
        uint4 g6 = fp[(size_t)rb.z * 16 + lane];
        uint4 g7 = fp[(size_t)rb.w * 16 + lane];
        ACC8(g0) ACC8(g1) ACC8(g2) ACC8(g3)
        ACC8(g4) ACC8(g5) ACC8(g6) ACC8(g7)
    }
    for (; j + 4 <= e1; j += 4) {
        int4 ra = rp4[j >> 2];
        uint4 g0 = fp[(size_t)ra.x * 16 + lane];
        uint4 g1 = fp[(size_t)ra.y * 16 + lane];
        uint4 g2 = fp[(size_t)ra.z * 16 + lane];
        uint4 g3 = fp[(size_t)ra.w * 16 + lane];
        ACC8(g0) ACC8(g1) ACC8(g2) ACC8(g3)
    }
    for (; j < e1; ++j) {
        int s = row[j];
        uint4 g0 = fp[(size_t)s * 16 + lane];
        ACC8(g0)
    }
#undef ACC8
    uint4 o;
    o.x = (uint_t)f2bf(a0) | ((uint_t)f2bf(a1) << 16);
    o.y = (uint_t)f2bf(a2) | ((uint_t)f2bf(a3) << 16);
    o.z = (uint_t)f2bf(a4) | ((uint_t)f2bf(a5) << 16);
    o.w = (uint_t)f2bf(a6) | ((uint_t)f2bf(a7) << 16);
    reinterpret_cast<uint4*>(hout)[(size_t)n * 16 + lane] = o;
}

// ---------------- fused MLP layer 1: hout = relu(relu(hin@Wa+ba)@Wb+bb) --------
__global__ __launch_bounds__(256) void mlp_kernel(const ushort_t* __restrict__ hin,
                                                  const ushort_t* __restrict__ wpA,
                                                  const float* __restrict__ ba,
                                                  const ushort_t* __restrict__ wpB,
                                                  const float* __restrict__ bb,
                                                  ushort_t* __restrict__ hout) {
    __shared__ ushort_t As[64 * LDA];
    int tid = threadIdx.x;
    int wave = tid >> 6;
    int lane = tid & 63;
    int quad = lane >> 4;
    int cl = lane & 15;
    int row0 = blockIdx.x * 64;

    bf16x8 B1[2][4], B2[2][4];
#pragma unroll
    for (int ti = 0; ti < 2; ++ti) {
        int t = 2 * wave + ti;
#pragma unroll
        for (int s = 0; s < 4; ++s) {
            B1[ti][s] = as_bf16x8(reinterpret_cast<const uint4*>(wpA)[(s * 8 + t) * 64 + lane]);
            B2[ti][s] = as_bf16x8(reinterpret_cast<const uint4*>(wpB)[(s * 8 + t) * 64 + lane]);
        }
    }

    for (int i = tid; i < 64 * 16; i += 256) {
        int r = i >> 4, c8 = i & 15;
        uint4 v = make_uint4(0u, 0u, 0u, 0u);
        int gr = row0 + r;
        if (gr < N_NODES)
            v = reinterpret_cast<const uint4*>(hin + (size_t)gr * DIM)[c8];
        *reinterpret_cast<uint4*>(&As[r * LDA + c8 * 8]) = v;
    }
    __syncthreads();

    f32x4 acc[4][2];
#pragma unroll
    for (int m = 0; m < 4; ++m)
#pragma unroll
        for (int ti = 0; ti < 2; ++ti)
#pragma unroll
            for (int r = 0; r < 4; ++r) acc[m][ti][r] = 0.f;

#pragma unroll
    for (int s = 0; s < 4; ++s) {
#pragma unroll
        for (int m = 0; m < 4; ++m) {
            bf16x8 a = *reinterpret_cast<const bf16x8*>(&As[(m * 16 + cl) * LDA + s * 32 + quad * 8]);
#pragma unroll
            for (int ti = 0; ti < 2; ++ti)
                acc[m][ti] = __builtin_amdgcn_mfma_f32_16x16x32_bf16(a, B1[ti][s], acc[m][ti], 0, 0, 0);
        }
    }
    __syncthreads();

#pragma unroll
    for (int ti = 0; ti < 2; ++ti) {
        int col = 32 * wave + ti * 16 + cl;
        float bv = ba[col];
#pragma unroll
        for (int m = 0; m < 4; ++m)
#pragma unroll
            for (int r = 0; r < 4; ++r) {
                float v = acc[m][ti][r] + bv;
                As[(m * 16 + quad * 4 + r) * LDA + col] = f2bf(fmaxf(v, 0.f));
            }
    }
    __syncthreads();

#pragma unroll
    for (int m = 0; m < 4; ++m)
#pragma unroll
        for (int ti = 0; ti < 2; ++ti)
#pragma unroll
            for (int r = 0; r < 4; ++r) acc[m][ti][r] = 0.f;

#pragma unroll
    for (int s = 0; s < 4; ++s) {
#pragma unroll
        for (int m = 0; m < 4; ++m) {
            bf16x8 a = *reinterpret_cast<const bf16x8*>(&As[(m * 16 + cl) * LDA + s * 32 + quad * 8]);
#pragma unroll
            for (int ti = 0; ti < 2; ++ti)
                acc[m][ti] = __builtin_amdgcn_mfma_f32_16x16x32_bf16(a, B2[ti][s], acc[m][ti], 0, 0, 0);
        }
    }

#pragma unroll
    for (int ti = 0; ti < 2; ++ti) {
        int col = 32 * wave + ti * 16 + cl;
        float bv = bb[col];
#pragma unroll
        for (int m = 0; m < 4; ++m)
#pragma unroll
            for (int r = 0; r < 4; ++r) {
                int gr = row0 + m * 16 + quad * 4 + r;
                if (gr < N_NODES) {
                    float v = acc[m][ti][r] + bv;
                    hout[(size_t)gr * DIM + col] = f2bf(fmaxf(v, 0.f));
                }
            }
    }
}

// ---------------- fused MLP layer 2 + per-graph pooling ----------------
__global__ __launch_bounds__(256) void mlp_pool_kernel(const ushort_t* __restrict__ hin,
                                                       const ushort_t* __restrict__ wpA,
                                                       const float* __restrict__ ba,
                                                       const ushort_t* __restrict__ wpB,
                                                       const float* __restrict__ bb,
                                                       const int* __restrict__ batch32,
                                                       float* __restrict__ gsum) {
    __shared__ ushort_t As[64 * LDA];
    int tid = threadIdx.x;
    int wave = tid >> 6;
    int lane = tid & 63;
    int quad = lane >> 4;
    int cl = lane & 15;
    int row0 = blockIdx.x * 64;

    bf16x8 B1[2][4], B2[2][4];
#pragma unroll
    for (int ti = 0; ti < 2; ++ti) {
        int t = 2 * wave + ti;
#pragma unroll
        for (int s = 0; s < 4; ++s) {
            B1[ti][s] = as_bf16x8(reinterpret_cast<const uint4*>(wpA)[(s * 8 + t) * 64 + lane]);
            B2[ti][s] = as_bf16x8(reinterpret_cast<const uint4*>(wpB)[(s * 8 + t) * 64 + lane]);
        }
    }

    for (int i = tid; i < 64 * 16; i += 256) {
        int r = i >> 4, c8 = i & 15;
        uint4 v = make_uint4(0u, 0u, 0u, 0u);
        int gr = row0 + r;
        if (gr < N_NODES)
            v = reinterpret_cast<const uint4*>(hin + (size_t)gr * DIM)[c8];
        *reinterpret_cast<uint4*>(&As[r * LDA + c8 * 8]) = v;
    }
    __syncthreads();

    f32x4 acc[4][2];
#pragma unroll
    for (int m = 0; m < 4; ++m)
#pragma unroll
        for (int ti = 0; ti < 2; ++ti)
#pragma unroll
            for (int r = 0; r < 4; ++r) acc[m][ti][r] = 0.f;

#pragma unroll
    for (int s = 0; s < 4; ++s) {
#pragma unroll
        for (int m = 0; m < 4; ++m) {
            bf16x8 a = *reinterpret_cast<const bf16x8*>(&As[(m * 16 + cl) * LDA + s * 32 + quad * 8]);
#pragma unroll
            for (int ti = 0; ti < 2; ++ti)
                acc[m][ti] = __builtin_amdgcn_mfma_f32_16x16x32_bf16(a, B1[ti][s], acc[m][ti], 0, 0, 0);
        }
    }
    __syncthreads();

#pragma unroll
    for (int ti = 0; ti < 2; ++ti) {
        int col = 32 * wave + ti * 16 + cl;
        float bv = ba[col];
#pragma unroll
        for (int m = 0; m < 4; ++m)
#pragma unroll
            for (int r = 0; r < 4; ++r) {
                float v = acc[m][ti][r] + bv;
                As[(m * 16 + quad * 4 + r) * LDA + col] = f2bf(fmaxf(v, 0.f));
            }
    }
    __syncthreads();

#pragma unroll
    for (int m = 0; m < 4; ++m)
#pragma unroll
        for (int ti = 0; ti < 2; ++ti)
#pragma unroll
            for (int r = 0; r < 4; ++r) acc[m][ti][r] = 0.f;

#pragma unroll
    for (int s = 0; s < 4; ++s) {
#pragma unroll
        for (int m = 0; m < 4; ++m) {
            bf16x8 a = *reinterpret_cast<const bf16x8*>(&As[(m * 16 + cl) * LDA + s * 32 + quad * 8]);
#pragma unroll
            for (int ti = 0; ti < 2; ++ti)
                acc[m][ti] = __builtin_amdgcn_mfma_f32_16x16x32_bf16(a, B2[ti][s], acc[m][ti], 0, 0, 0);
        }
    }
    __syncthreads();  // all As reads of GEMM2 done before epilogue overwrite

#pragma unroll
    for (int ti = 0; ti < 2; ++ti) {
        int col = 32 * wave + ti * 16 + cl;
        float bv = bb[col];
#pragma unroll
        for (int m = 0; m < 4; ++m)
#pragma unroll
            for (int r = 0; r < 4; ++r) {
                float v = acc[m][ti][r] + bv;
                As[(m * 16 + quad * 4 + r) * LDA + col] = f2bf(fmaxf(v, 0.f));
            }
    }
    __syncthreads();

    // pooling: thread t handles col c over 32 rows; flush per graph segment
    int c = tid & 127;
    int rbase = (tid >> 7) * 32;
    float accp = 0.f;
    int curg = -1;
    for (int r = rbase; r < rbase + 32; ++r) {
        int gr = row0 + r;
        if (gr >= N_NODES) break;
        int g = batch32[gr];
        if (g != curg) {
            if (curg >= 0) atomicAdd(&gsum[curg * DIM + c], accp);
            curg = g;
            accp = 0.f;
        }
        accp += bf2f(As[r * LDA + c]);
    }
    if (curg >= 0) atomicAdd(&gsum[curg * DIM + c], accp);
}

// ---------------- final FC: out[g] = (gsum[g]/count[g]) @ Wfc + bfc ----------------
__global__ __launch_bounds__(64) void fc_kernel(const float* __restrict__ gsum,
                                                const int* __restrict__ batch,
                                                const float* __restrict__ params,
                                                const int* __restrict__ flags,
                                                void* __restrict__ out) {
    int g = blockIdx.x;
    int l = threadIdx.x;
    int lo = 0, hi = N_NODES;
    while (lo < hi) { int mid = (lo + hi) >> 1; if (batch[mid] < g) lo = mid + 1; else hi = mid; }
    int start = lo;
    hi = N_NODES;
    while (lo < hi) { int mid = (lo + hi) >> 1; if (batch[mid] < g + 1) lo = mid + 1; else hi = mid; }
    int cnt = lo - start;
    float inv = 1.0f / (float)(cnt > 0 ? cnt : 1);
    float m0 = gsum[g * DIM + l] * inv;
    float m1 = gsum[g * DIM + 64 + l] * inv;
    float p0 = m0 * params[512 + l * 2 + 0] + m1 * params[512 + (64 + l) * 2 + 0];
    float p1 = m0 * params[512 + l * 2 + 1] + m1 * params[512 + (64 + l) * 2 + 1];
#pragma unroll
    for (int off = 32; off > 0; off >>= 1) {
        p0 += __shfl_down(p0, off, 64);
        p1 += __shfl_down(p1, off, 64);
    }
    if (l == 0) {
        float o0 = p0 + params[768];
        float o1 = p1 + params[769];
        if (flags[0]) {
            ((float*)out)[g * 2 + 0] = o0;
            ((float*)out)[g * 2 + 1] = o1;
        } else {
            ((ushort_t*)out)[g * 2 + 0] = f2bf(o0);
            ((ushort_t*)out)[g * 2 + 1] = f2bf(o1);
        }
    }
}

extern "C" void kernel_launch(void* const* d_in, const int* in_sizes, int n_in,
                              void* d_out, int out_size, void* d_ws, size_t ws_size,
                              hipStream_t stream) {
    const void* x = d_in[0];
    const void* ei = d_in[1];
    const void* batch = d_in[2];
    const void* W1a = d_in[3];
    const void* b1a = d_in[4];
    const void* W1b = d_in[5];
    const void* b1b = d_in[6];
    const void* W2a = d_in[7];
    const void* b2a = d_in[8];
    const void* W2b = d_in[9];
    const void* b2b = d_in[10];
    const void* Wfc = d_in[11];
    const void* bfc = d_in[12];

    // Workspace layout (~47 MB, all chunks 16B-aligned; ws is 256MB per harness fill)
    char* base = (char*)d_ws;
    ushort_t* hX = (ushort_t*)base;   base += (size_t)N_NODES * DIM * 2;       // 12.8 MB (f32 input only)
    ushort_t* hA = (ushort_t*)base;   base += (size_t)N_NODES * DIM * 2;       // 12.8 MB
    int* ell = (int*)base;            base += (size_t)N_NODES * ELL_CAP * 4;   // 12.8 MB
    int2* fifo = (int2*)base;         base += (size_t)EDGE_GROUPS * FIFO_CAP * 8;  // 7.1 MB
    int* cnt = (int*)base;            base += (size_t)N_NODES * 4;
    int* batch32 = (int*)base;        base += (size_t)N_NODES * 4;
    int* gcnt = (int*)base;           base += 64;
    ushort_t* wp = (ushort_t*)base;   base += 4 * 16384 * 2;
    float* params = (float*)base;     base += 772 * 4;
    float* gsum = (float*)base;       base += (size_t)NUM_GRAPHS * DIM * 4;    // 256 KB
    int* flags = (int*)base;          base += 16;

    ushort_t* wpA1 = wp;
    ushort_t* wpB1 = wp + 16384;
    ushort_t* wpA2 = wp + 2 * 16384;
    ushort_t* wpB2 = wp + 3 * 16384;

    // Zero degree+gsum+group counters, detect dtypes
    zero_detect_kernel<<<256, 256, 0, stream>>>(cnt, gsum, gcnt, x, ei, flags);
    // Pass A: edge partition into per-XCD FIFOs + canonicalization (x, W, batch, params)
    prep_all_kernel<<<PREP_TOTAL, 256, 0, stream>>>(x, batch, ei, W1a, W1b, W2a, W2b,
                                                    b1a, b1b, b2a, b2b, Wfc, bfc, flags,
                                                    hX, wp, batch32, params, gcnt, fifo);
    // Pass B: dense XCD-local ELL scatter
    scatter_kernel<<<SCATTER_BLOCKS, 256, 0, stream>>>(fifo, gcnt, cnt, ell);

    // Layer 1: agg(x)->hA (reads raw input in place when bf16), mlp in-place on hA
    agg_kernel<<<(N_NODES + 15) / 16, 256, 0, stream>>>(hX, x, flags, cnt, ell, hA);
    mlp_kernel<<<(N_NODES + 63) / 64, 256, 0, stream>>>(hA, wpA1, params + 0, wpB1, params + 128, hA);
    // Layer 2: agg(hA)->hX, then MLP+pool fused (no h2 global write)
    agg_kernel<<<(N_NODES + 15) / 16, 256, 0, stream>>>(hA, hA, nullptr, cnt, ell, hX);
    mlp_pool_kernel<<<(N_NODES + 63) / 64, 256, 0, stream>>>(hX, wpA2, params + 256, wpB2, params + 384,
                                                             batch32, gsum);
    // Final FC from pooled sums
    fc_kernel<<<NUM_GRAPHS, 64, 0, stream>>>(gsum, batch32, params, flags, d_out);
}

// Round 5
// 228.159 us; speedup vs baseline: 1.0847x; 1.0847x over previous
//
#include <hip/hip_runtime.h>

typedef unsigned short ushort_t;
typedef unsigned int uint_t;

typedef __bf16 bf16x8 __attribute__((ext_vector_type(8)));
typedef float f32x4 __attribute__((ext_vector_type(4)));

#define N_NODES 50000
#define N_EDGES 800000
#define DIM 128
#define NUM_GRAPHS 512
#define LDA 136  // padded LDS row stride in bf16 elems (128+8)

// ELL adjacency: fixed 64 slots per node (in-degree ~Poisson(16), max ~35;
// P(deg>64) astronomically small. Guarded anyway: overflow slots dropped.)
#define ELL_CAP 64

// Two-phase edge build with LDS slot counters (round-5 design):
//  R3/R4 lesson: ~800K GLOBAL atomicAdds have a ~20us throughput floor
//  (~2/cyc/XCD) regardless of bucketing structure. Fix: one block owns one
//  dst-bucket, so slot counters live in LDS (fast RMW), zero global atomics
//  on the scatter path.
//  Pass A (in prep_all): partition edges into 256 bucket-FIFOs; entries are
//    PACKED 4B: src (16b, 50000<2^16) | d_local (<196) << 16.
//  Pass B (scatter_kernel): block b owns bucket b (196 nodes): zero LDS
//    counters, stream FIFO, LDS-atomic slot, store ell, dump cnt wholesale
//    (so cnt needs no pre-zeroing).
#define NBUCK 256
#define BUCK_SZ 196          // ceil(50000/256)
#define FIFO_CAP 4096        // avg 3125/bucket, sigma ~56 -> +17 sigma margin
#define A_CHUNK 2048
#define A_BLOCKS ((N_EDGES + A_CHUNK - 1) / A_CHUNK)             // 391

// prep_all block ranges (edge-partition blocks first: critical path)
#define PREP_X_BLOCKS 6250                    // conv_x: only does work when f32 input
#define PREP_W_BLOCKS 256                     // wperm: 65536 / 256
#define PREP_B_BLOCKS 196                     // batch: 50000 / 256
#define PREP_TOTAL (A_BLOCKS + PREP_X_BLOCKS + PREP_W_BLOCKS + PREP_B_BLOCKS + 1)

__device__ __forceinline__ float bf2f(ushort_t u) {
    return __uint_as_float(((uint_t)u) << 16);
}
__device__ __forceinline__ ushort_t f2bf(float f) {
    uint_t u = __float_as_uint(f);
    u = (u + 0x7FFF + ((u >> 16) & 1)) >> 16;  // RNE
    return (ushort_t)u;
}
__device__ __forceinline__ bf16x8 as_bf16x8(uint4 v) {
    return __builtin_bit_cast(bf16x8, v);
}

// ---------------- zero (gsum + fifo counters) + dtype detection ----------------
// cnt no longer needs zeroing: scatter_kernel writes every node's count.
__global__ void zero_detect_kernel(float* gsum, int* gcnt, const void* xraw,
                                   const void* eiraw, int* flags) {
    int i = blockIdx.x * 256 + threadIdx.x;
    if (i < NUM_GRAPHS * DIM) gsum[i] = 0.f;
    if (i < NBUCK) gcnt[i] = 0;
    if (i == 0) {
        const ushort_t* u = (const ushort_t*)xraw;
        int extreme = 0;
        for (int k = 0; k < 128; ++k) {
            int e = (u[k] >> 7) & 0xFF;
            if (e >= 0xC0) extreme++;  // |x| >= 2^65: impossible for bf16 N(0,1)
        }
        flags[0] = (extreme > 8) ? 1 : 0;
        const int* p = (const int*)eiraw;
        int nonzero = 0;
        for (int k = 1; k < 64; k += 2) nonzero += (p[k] != 0);
        flags[1] = (nonzero == 0) ? 1 : 0;  // all high-halves zero => int64
    }
}

// ---------------- merged canonicalization + edge partition (pass A) ----------------
__global__ __launch_bounds__(256) void prep_all_kernel(
    const void* xraw, const void* braw, const void* eiraw,
    const void* W0, const void* W1, const void* W2, const void* W3,
    const void* pb1a, const void* pb1b, const void* pb2a, const void* pb2b,
    const void* pWfc, const void* pbfc, const int* __restrict__ flags,
    ushort_t* __restrict__ xout, ushort_t* __restrict__ wpout,
    int* __restrict__ batch32, float* __restrict__ params,
    int* __restrict__ gcnt, uint_t* __restrict__ fifo) {
    __shared__ int lcnt[NBUCK];
    __shared__ int lbase[NBUCK];
    int b = blockIdx.x;
    int tid = threadIdx.x;
    if (b < A_BLOCKS) {
        lcnt[tid] = 0;
        __syncthreads();
        const int* p = (const int*)eiraw;
        int i64 = flags[1];
        int base_e = b * A_CHUNK;
        int gk[8], rk[8];
        uint_t pk[8];
#pragma unroll
        for (int k = 0; k < 8; ++k) {
            int e = base_e + k * 256 + tid;
            int valid = e < N_EDGES;
            int s = 0, d = 0;
            if (valid) {
                if (i64) { s = p[2 * e]; d = p[2 * (N_EDGES + e)]; }
                else     { s = p[e];     d = p[N_EDGES + e]; }
            }
            int g = d / BUCK_SZ;                       // 0..255 (magic-mul)
            gk[k] = valid ? g : -1;
            pk[k] = (uint_t)s | ((uint_t)(d - g * BUCK_SZ) << 16);
            rk[k] = valid ? atomicAdd(&lcnt[g], 1) : 0;
        }
        __syncthreads();
        lbase[tid] = atomicAdd(&gcnt[tid], lcnt[tid]);  // block reservation
        __syncthreads();
#pragma unroll
        for (int k = 0; k < 8; ++k) {
            if (gk[k] >= 0) {
                int pos = lbase[gk[k]] + rk[k];
                if (pos < FIFO_CAP)
                    fifo[(size_t)gk[k] * FIFO_CAP + pos] = pk[k];
            }
        }
    } else if (b < A_BLOCKS + PREP_X_BLOCKS) {
        if (flags[0]) {  // only f32 input needs conversion; bf16 is read in place
            int i = (b - A_BLOCKS) * 256 + tid;
            if (i < N_NODES * DIM / 4) {
                float4 v = ((const float4*)xraw)[i];
                ushort4 o;
                o.x = f2bf(v.x); o.y = f2bf(v.y); o.z = f2bf(v.z); o.w = f2bf(v.w);
                ((ushort4*)xout)[i] = o;
            }
        }
    } else if (b < A_BLOCKS + PREP_X_BLOCKS + PREP_W_BLOCKS) {
        int gidx = (b - A_BLOCKS - PREP_X_BLOCKS) * 256 + tid;  // 0..65535
        int which = gidx >> 14;
        const void* W = (which == 0) ? W0 : (which == 1) ? W1 : (which == 2) ? W2 : W3;
        int idx = gidx & 16383;
        int j = idx & 7;
        int L = (idx >> 3) & 63;
        int t = (idx >> 9) & 7;
        int s = idx >> 12;
        int k = s * 32 + (L >> 4) * 8 + j;
        int n = t * 16 + (L & 15);
        int off = k * DIM + n;
        wpout[gidx] = flags[0] ? f2bf(((const float*)W)[off]) : ((const ushort_t*)W)[off];
    } else if (b < A_BLOCKS + PREP_X_BLOCKS + PREP_W_BLOCKS + PREP_B_BLOCKS) {
        int i = (b - A_BLOCKS - PREP_X_BLOCKS - PREP_W_BLOCKS) * 256 + tid;
        if (i < N_NODES) {
            const int* p = (const int*)braw;
            batch32[i] = flags[1] ? p[2 * i] : p[i];
        }
    } else {
        for (int i = tid; i < 770; i += 256) {
            const void* srcp;
            int j;
            if (i < 128)      { srcp = pb1a; j = i; }
            else if (i < 256) { srcp = pb1b; j = i - 128; }
            else if (i < 384) { srcp = pb2a; j = i - 256; }
            else if (i < 512) { srcp = pb2b; j = i - 384; }
            else if (i < 768) { srcp = pWfc; j = i - 512; }
            else              { srcp = pbfc; j = i - 768; }
            params[i] = flags[0] ? ((const float*)srcp)[j] : bf2f(((const ushort_t*)srcp)[j]);
        }
    }
}

// ---------------- pass B: per-bucket ELL scatter with LDS slot counters --------
// Block b exclusively owns nodes [b*196, (b+1)*196): slot RMW in LDS (fast),
// zero global atomics. Dumps cnt wholesale -> no pre-zero of cnt needed.
__global__ __launch_bounds__(256) void scatter_kernel(const uint_t* __restrict__ fifo,
                                                      const int* __restrict__ gcnt,
                                                      int* __restrict__ cnt,
                                                      int* __restrict__ ell) {
    __shared__ int lcnt[BUCK_SZ];
    int b = blockIdx.x;
    int tid = threadIdx.x;
    if (tid < BUCK_SZ) lcnt[tid] = 0;
    __syncthreads();
    int n = gcnt[b];
    if (n > FIFO_CAP) n = FIFO_CAP;
    const uint_t* f = fifo + (size_t)b * FIFO_CAP;
    int node0 = b * BUCK_SZ;
    for (int i = tid; i < n; i += 256) {
        uint_t e = f[i];
        int s = (int)(e & 0xFFFFu);
        int dl = (int)(e >> 16);
        int slot = atomicAdd(&lcnt[dl], 1);
        if (slot < ELL_CAP) ell[(size_t)(node0 + dl) * ELL_CAP + slot] = s;
    }
    __syncthreads();
    if (tid < BUCK_SZ) {
        int node = node0 + tid;
        if (node < N_NODES) cnt[node] = lcnt[tid];
    }
}

// ---------------- aggregation: h[n] = feat[n] + sum_{j in in-edges} feat[src_j] ----
// Standalone (NOT fused into the GEMM): 16 nodes/block x 3125 blocks keeps
// full occupancy to hide random-gather latency (round-2 lesson: fusing into
// the 782-block MLP grid dropped occupancy to 20%, +25us). Quarter-wave
// (16 lanes) per node, uint4 per lane, unroll-8 = 32 gathers in flight/wave.
// ELL indices fetched as int4 (2 VMEM ops per 8 edges).
__global__ __launch_bounds__(256) void agg_kernel(const ushort_t* __restrict__ featA,
                                                  const void* __restrict__ featB,
                                                  const int* __restrict__ flags,
                                                  const int* __restrict__ deg,
                                                  const int* __restrict__ ell,
                                                  ushort_t* __restrict__ hout) {
    int n = blockIdx.x * 16 + (threadIdx.x >> 4);
    int lane = threadIdx.x & 15;
    if (n >= N_NODES) return;
    // flags==nullptr -> use featA; else select converted vs raw-bf16 input
    const ushort_t* feat = featA;
    if (flags && !flags[0]) feat = (const ushort_t*)featB;
    const uint4* fp = reinterpret_cast<const uint4*>(feat);  // row = 16 x uint4
    uint4 v = fp[(size_t)n * 16 + lane];
    float a0 = bf2f((ushort_t)(v.x & 0xffff));
    float a1 = bf2f((ushort_t)(v.x >> 16));
    float a2 = bf2f((ushort_t)(v.y & 0xffff));
    float a3 = bf2f((ushort_t)(v.y >> 16));
    float a4 = bf2f((ushort_t)(v.z & 0xffff));
    float a5 = bf2f((ushort_t)(v.z >> 16));
    float a6 = bf2f((ushort_t)(v.w & 0xffff));
    float a7 = bf2f((ushort_t)(v.w >> 16));
    int e1 = deg[n];
    if (e1 > ELL_CAP) e1 = ELL_CAP;
    const int4* __restrict__ rp4 = reinterpret_cast<const int4*>(ell + (size_t)n * ELL_CAP);
    const int* __restrict__ row = ell + (size_t)n * ELL_CAP;
    int j = 0;
#define ACC8(V) \
    a0 += bf2f((ushort_t)((V).x & 0xffff)); a1 += bf2f((ushort_t)((V).x >> 16)); \
    a2 += bf2f((ushort_t)((V).y & 0xffff)); a3 += bf2f((ushort_t)((V).y >> 16)); \
    a4 += bf2f((ushort_t)((V).z & 0xffff)); a5 += bf2f((ushort_t)((V).z >> 16)); \
    a6 += bf2f((ushort_t)((V).w & 0xffff)); a7 += bf2f((ushort_t)((V).w >> 16));
    for (; j + 8 <= e1; j += 8) {
        int4 ra = rp4[j >> 2];
        int4 rb = rp4[(j >> 2) + 1];
        uint4 g0 = fp[(size_t)ra.x * 16 + lane];
        uint4 g1 = fp[(size_t)ra.y * 16 + lane];
        uint4 g2 = fp[(size_t)ra.z * 16 + lane];
        uint4 g3 = fp[(size_t)ra.w * 16 + lane];
        uint4 g4 = fp[(size_t)rb.x * 16 + lane];
        uint4 g5 = fp[(size_t)rb.y * 16 + lane];
        uint4 g6 = fp[(size_t)rb.z * 16 + lane];
        uint4 g7 = fp[(size_t)rb.w * 16 + lane];
        ACC8(g0) ACC8(g1) ACC8(g2) ACC8(g3)
        ACC8(g4) ACC8(g5) ACC8(g6) ACC8(g7)
    }
    for (; j + 4 <= e1; j += 4) {
        int4 ra = rp4[j >> 2];
        uint4 g0 = fp[(size_t)ra.x * 16 + lane];
        uint4 g1 = fp[(size_t)ra.y * 16 + lane];
        uint4 g2 = fp[(size_t)ra.z * 16 + lane];
        uint4 g3 = fp[(size_t)ra.w * 16 + lane];
        ACC8(g0) ACC8(g1) ACC8(g2) ACC8(g3)
    }
    for (; j < e1; ++j) {
        int s = row[j];
        uint4 g0 = fp[(size_t)s * 16 + lane];
        ACC8(g0)
    }
#undef ACC8
    uint4 o;
    o.x = (uint_t)f2bf(a0) | ((uint_t)f2bf(a1) << 16);
    o.y = (uint_t)f2bf(a2) | ((uint_t)f2bf(a3) << 16);
    o.z = (uint_t)f2bf(a4) | ((uint_t)f2bf(a5) << 16);
    o.w = (uint_t)f2bf(a6) | ((uint_t)f2bf(a7) << 16);
    reinterpret_cast<uint4*>(hout)[(size_t)n * 16 + lane] = o;
}

// ---------------- fused MLP layer 1: hout = relu(relu(hin@Wa+ba)@Wb+bb) --------
__global__ __launch_bounds__(256) void mlp_kernel(const ushort_t* __restrict__ hin,
                                                  const ushort_t* __restrict__ wpA,
                                                  const float* __restrict__ ba,
                                                  const ushort_t* __restrict__ wpB,
                                                  const float* __restrict__ bb,
                                                  ushort_t* __restrict__ hout) {
    __shared__ ushort_t As[64 * LDA];
    int tid = threadIdx.x;
    int wave = tid >> 6;
    int lane = tid & 63;
    int quad = lane >> 4;
    int cl = lane & 15;
    int row0 = blockIdx.x * 64;

    bf16x8 B1[2][4], B2[2][4];
#pragma unroll
    for (int ti = 0; ti < 2; ++ti) {
        int t = 2 * wave + ti;
#pragma unroll
        for (int s = 0; s < 4; ++s) {
            B1[ti][s] = as_bf16x8(reinterpret_cast<const uint4*>(wpA)[(s * 8 + t) * 64 + lane]);
            B2[ti][s] = as_bf16x8(reinterpret_cast<const uint4*>(wpB)[(s * 8 + t) * 64 + lane]);
        }
    }

    for (int i = tid; i < 64 * 16; i += 256) {
        int r = i >> 4, c8 = i & 15;
        uint4 v = make_uint4(0u, 0u, 0u, 0u);
        int gr = row0 + r;
        if (gr < N_NODES)
            v = reinterpret_cast<const uint4*>(hin + (size_t)gr * DIM)[c8];
        *reinterpret_cast<uint4*>(&As[r * LDA + c8 * 8]) = v;
    }
    __syncthreads();

    f32x4 acc[4][2];
#pragma unroll
    for (int m = 0; m < 4; ++m)
#pragma unroll
        for (int ti = 0; ti < 2; ++ti)
#pragma unroll
            for (int r = 0; r < 4; ++r) acc[m][ti][r] = 0.f;

#pragma unroll
    for (int s = 0; s < 4; ++s) {
#pragma unroll
        for (int m = 0; m < 4; ++m) {
            bf16x8 a = *reinterpret_cast<const bf16x8*>(&As[(m * 16 + cl) * LDA + s * 32 + quad * 8]);
#pragma unroll
            for (int ti = 0; ti < 2; ++ti)
                acc[m][ti] = __builtin_amdgcn_mfma_f32_16x16x32_bf16(a, B1[ti][s], acc[m][ti], 0, 0, 0);
        }
    }
    __syncthreads();

#pragma unroll
    for (int ti = 0; ti < 2; ++ti) {
        int col = 32 * wave + ti * 16 + cl;
        float bv = ba[col];
#pragma unroll
        for (int m = 0; m < 4; ++m)
#pragma unroll
            for (int r = 0; r < 4; ++r) {
                float v = acc[m][ti][r] + bv;
                As[(m * 16 + quad * 4 + r) * LDA + col] = f2bf(fmaxf(v, 0.f));
            }
    }
    __syncthreads();

#pragma unroll
    for (int m = 0; m < 4; ++m)
#pragma unroll
        for (int ti = 0; ti < 2; ++ti)
#pragma unroll
            for (int r = 0; r < 4; ++r) acc[m][ti][r] = 0.f;

#pragma unroll
    for (int s = 0; s < 4; ++s) {
#pragma unroll
        for (int m = 0; m < 4; ++m) {
            bf16x8 a = *reinterpret_cast<const bf16x8*>(&As[(m * 16 + cl) * LDA + s * 32 + quad * 8]);
#pragma unroll
            for (int ti = 0; ti < 2; ++ti)
                acc[m][ti] = __builtin_amdgcn_mfma_f32_16x16x32_bf16(a, B2[ti][s], acc[m][ti], 0, 0, 0);
        }
    }

#pragma unroll
    for (int ti = 0; ti < 2; ++ti) {
        int col = 32 * wave + ti * 16 + cl;
        float bv = bb[col];
#pragma unroll
        for (int m = 0; m < 4; ++m)
#pragma unroll
            for (int r = 0; r < 4; ++r) {
                int gr = row0 + m * 16 + quad * 4 + r;
                if (gr < N_NODES) {
                    float v = acc[m][ti][r] + bv;
                    hout[(size_t)gr * DIM + col] = f2bf(fmaxf(v, 0.f));
                }
            }
    }
}

// ---------------- fused MLP layer 2 + per-graph pooling ----------------
__global__ __launch_bounds__(256) void mlp_pool_kernel(const ushort_t* __restrict__ hin,
                                                       const ushort_t* __restrict__ wpA,
                                                       const float* __restrict__ ba,
                                                       const ushort_t* __restrict__ wpB,
                                                       const float* __restrict__ bb,
                                                       const int* __restrict__ batch32,
                                                       float* __restrict__ gsum) {
    __shared__ ushort_t As[64 * LDA];
    int tid = threadIdx.x;
    int wave = tid >> 6;
    int lane = tid & 63;
    int quad = lane >> 4;
    int cl = lane & 15;
    int row0 = blockIdx.x * 64;

    bf16x8 B1[2][4], B2[2][4];
#pragma unroll
    for (int ti = 0; ti < 2; ++ti) {
        int t = 2 * wave + ti;
#pragma unroll
        for (int s = 0; s < 4; ++s) {
            B1[ti][s] = as_bf16x8(reinterpret_cast<const uint4*>(wpA)[(s * 8 + t) * 64 + lane]);
            B2[ti][s] = as_bf16x8(reinterpret_cast<const uint4*>(wpB)[(s * 8 + t) * 64 + lane]);
        }
    }

    for (int i = tid; i < 64 * 16; i += 256) {
        int r = i >> 4, c8 = i & 15;
        uint4 v = make_uint4(0u, 0u, 0u, 0u);
        int gr = row0 + r;
        if (gr < N_NODES)
            v = reinterpret_cast<const uint4*>(hin + (size_t)gr * DIM)[c8];
        *reinterpret_cast<uint4*>(&As[r * LDA + c8 * 8]) = v;
    }
    __syncthreads();

    f32x4 acc[4][2];
#pragma unroll
    for (int m = 0; m < 4; ++m)
#pragma unroll
        for (int ti = 0; ti < 2; ++ti)
#pragma unroll
            for (int r = 0; r < 4; ++r) acc[m][ti][r] = 0.f;

#pragma unroll
    for (int s = 0; s < 4; ++s) {
#pragma unroll
        for (int m = 0; m < 4; ++m) {
            bf16x8 a = *reinterpret_cast<const bf16x8*>(&As[(m * 16 + cl) * LDA + s * 32 + quad * 8]);
#pragma unroll
            for (int ti = 0; ti < 2; ++ti)
                acc[m][ti] = __builtin_amdgcn_mfma_f32_16x16x32_bf16(a, B1[ti][s], acc[m][ti], 0, 0, 0);
        }
    }
    __syncthreads();

#pragma unroll
    for (int ti = 0; ti < 2; ++ti) {
        int col = 32 * wave + ti * 16 + cl;
        float bv = ba[col];
#pragma unroll
        for (int m = 0; m < 4; ++m)
#pragma unroll
            for (int r = 0; r < 4; ++r) {
                float v = acc[m][ti][r] + bv;
                As[(m * 16 + quad * 4 + r) * LDA + col] = f2bf(fmaxf(v, 0.f));
            }
    }
    __syncthreads();

#pragma unroll
    for (int m = 0; m < 4; ++m)
#pragma unroll
        for (int ti = 0; ti < 2; ++ti)
#pragma unroll
            for (int r = 0; r < 4; ++r) acc[m][ti][r] = 0.f;

#pragma unroll
    for (int s = 0; s < 4; ++s) {
#pragma unroll
        for (int m = 0; m < 4; ++m) {
            bf16x8 a = *reinterpret_cast<const bf16x8*>(&As[(m * 16 + cl) * LDA + s * 32 + quad * 8]);
#pragma unroll
            for (int ti = 0; ti < 2; ++ti)
                acc[m][ti] = __builtin_amdgcn_mfma_f32_16x16x32_bf16(a, B2[ti][s], acc[m][ti], 0, 0, 0);
        }
    }
    __syncthreads();  // all As reads of GEMM2 done before epilogue overwrite

#pragma unroll
    for (int ti = 0; ti < 2; ++ti) {
        int col = 32 * wave + ti * 16 + cl;
        float bv = bb[col];
#pragma unroll
        for (int m = 0; m < 4; ++m)
#pragma unroll
            for (int r = 0; r < 4; ++r) {
                float v = acc[m][ti][r] + bv;
                As[(m * 16 + quad * 4 + r) * LDA + col] = f2bf(fmaxf(v, 0.f));
            }
    }
    __syncthreads();

    // pooling: thread t handles col c over 32 rows; flush per graph segment
    int c = tid & 127;
    int rbase = (tid >> 7) * 32;
    float accp = 0.f;
    int curg = -1;
    for (int r = rbase; r < rbase + 32; ++r) {
        int gr = row0 + r;
        if (gr >= N_NODES) break;
        int g = batch32[gr];
        if (g != curg) {
            if (curg >= 0) atomicAdd(&gsum[curg * DIM + c], accp);
            curg = g;
            accp = 0.f;
        }
        accp += bf2f(As[r * LDA + c]);
    }
    if (curg >= 0) atomicAdd(&gsum[curg * DIM + c], accp);
}

// ---------------- final FC: out[g] = (gsum[g]/count[g]) @ Wfc + bfc ----------------
__global__ __launch_bounds__(64) void fc_kernel(const float* __restrict__ gsum,
                                                const int* __restrict__ batch,
                                                const float* __restrict__ params,
                                                const int* __restrict__ flags,
                                                void* __restrict__ out) {
    int g = blockIdx.x;
    int l = threadIdx.x;
    int lo = 0, hi = N_NODES;
    while (lo < hi) { int mid = (lo + hi) >> 1; if (batch[mid] < g) lo = mid + 1; else hi = mid; }
    int start = lo;
    hi = N_NODES;
    while (lo < hi) { int mid = (lo + hi) >> 1; if (batch[mid] < g + 1) lo = mid + 1; else hi = mid; }
    int cnt = lo - start;
    float inv = 1.0f / (float)(cnt > 0 ? cnt : 1);
    float m0 = gsum[g * DIM + l] * inv;
    float m1 = gsum[g * DIM + 64 + l] * inv;
    float p0 = m0 * params[512 + l * 2 + 0] + m1 * params[512 + (64 + l) * 2 + 0];
    float p1 = m0 * params[512 + l * 2 + 1] + m1 * params[512 + (64 + l) * 2 + 1];
#pragma unroll
    for (int off = 32; off > 0; off >>= 1) {
        p0 += __shfl_down(p0, off, 64);
        p1 += __shfl_down(p1, off, 64);
    }
    if (l == 0) {
        float o0 = p0 + params[768];
        float o1 = p1 + params[769];
        if (flags[0]) {
            ((float*)out)[g * 2 + 0] = o0;
            ((float*)out)[g * 2 + 1] = o1;
        } else {
            ((ushort_t*)out)[g * 2 + 0] = f2bf(o0);
            ((ushort_t*)out)[g * 2 + 1] = f2bf(o1);
        }
    }
}

extern "C" void kernel_launch(void* const* d_in, const int* in_sizes, int n_in,
                              void* d_out, int out_size, void* d_ws, size_t ws_size,
                              hipStream_t stream) {
    const void* x = d_in[0];
    const void* ei = d_in[1];
    const void* batch = d_in[2];
    const void* W1a = d_in[3];
    const void* b1a = d_in[4];
    const void* W1b = d_in[5];
    const void* b1b = d_in[6];
    const void* W2a = d_in[7];
    const void* b2a = d_in[8];
    const void* W2b = d_in[9];
    const void* b2b = d_in[10];
    const void* Wfc = d_in[11];
    const void* bfc = d_in[12];

    // Workspace layout (~44 MB, all chunks 16B-aligned)
    char* base = (char*)d_ws;
    ushort_t* hX = (ushort_t*)base;   base += (size_t)N_NODES * DIM * 2;       // 12.8 MB (f32 input only)
    ushort_t* hA = (ushort_t*)base;   base += (size_t)N_NODES * DIM * 2;       // 12.8 MB
    int* ell = (int*)base;            base += (size_t)N_NODES * ELL_CAP * 4;   // 12.8 MB
    uint_t* fifo = (uint_t*)base;     base += (size_t)NBUCK * FIFO_CAP * 4;    // 4 MB
    int* cnt = (int*)base;            base += (size_t)N_NODES * 4;
    int* batch32 = (int*)base;        base += (size_t)N_NODES * 4;
    int* gcnt = (int*)base;           base += NBUCK * 4;
    ushort_t* wp = (ushort_t*)base;   base += 4 * 16384 * 2;
    float* params = (float*)base;     base += 772 * 4;
    float* gsum = (float*)base;       base += (size_t)NUM_GRAPHS * DIM * 4;    // 256 KB
    int* flags = (int*)base;          base += 16;

    ushort_t* wpA1 = wp;
    ushort_t* wpB1 = wp + 16384;
    ushort_t* wpA2 = wp + 2 * 16384;
    ushort_t* wpB2 = wp + 3 * 16384;

    // Zero gsum+bucket counters, detect dtypes (cnt is written wholesale by scatter)
    zero_detect_kernel<<<256, 256, 0, stream>>>(gsum, gcnt, x, ei, flags);
    // Pass A: edge partition into 256 packed bucket-FIFOs + canonicalization
    prep_all_kernel<<<PREP_TOTAL, 256, 0, stream>>>(x, batch, ei, W1a, W1b, W2a, W2b,
                                                    b1a, b1b, b2a, b2b, Wfc, bfc, flags,
                                                    hX, wp, batch32, params, gcnt, fifo);
    // Pass B: per-bucket ELL scatter, slot counters in LDS (no global atomics)
    scatter_kernel<<<NBUCK, 256, 0, stream>>>(fifo, gcnt, cnt, ell);

    // Layer 1: agg(x)->hA (reads raw input in place when bf16), mlp in-place on hA
    agg_kernel<<<(N_NODES + 15) / 16, 256, 0, stream>>>(hX, x, flags, cnt, ell, hA);
    mlp_kernel<<<(N_NODES + 63) / 64, 256, 0, stream>>>(hA, wpA1, params + 0, wpB1, params + 128, hA);
    // Layer 2: agg(hA)->hX, then MLP+pool fused (no h2 global write)
    agg_kernel<<<(N_NODES + 15) / 16, 256, 0, stream>>>(hA, hA, nullptr, cnt, ell, hX);
    mlp_pool_kernel<<<(N_NODES + 63) / 64, 256, 0, stream>>>(hX, wpA2, params + 256, wpB2, params + 384,
                                                             batch32, gsum);
    // Final FC from pooled sums
    fc_kernel<<<NUM_GRAPHS, 64, 0, stream>>>(gsum, batch32, params, flags, d_out);
}